// Round 2
// baseline (654.028 us; speedup 1.0000x reference)
//
#include <hip/hip_runtime.h>
#include <math.h>

// Dale CB-cell recurrent update. H=48, IN=8, B=1048576, DT=0.1, fp32.
//
// R2 structure: one lane per batch element; SINGLE fused k-pass updating both
// accumulators (z-path and v-path) -> 96 FMAs per r[k]. r packed as bf16x2 in
// LDS (24KB/block -> occupancy cap moves to VGPR ~4 waves/SIMD). v is NOT kept
// live; hidden is re-read in the epilogue (L3-resident) behind an asm opacity
// barrier. Weights stream as wave-uniform s_loads from a k-major interleaved
// layout in ws.

#define DTC 0.1f

// ws layout (floats):
//   [0    , 4608) WB[k*96 + h]     = softplus(K)[h][k]   (h<48)
//                 WB[k*96 + 48 +h] = Dale W[h][k]
//   [4608 , 5376) PB[j*96 + h]     = P_z[h][j]
//                 PB[j*96 + 48 +h] = (P*mask)[h][j]
//   [5376 , 5472) bb[h] = b_z[h] ; bb[48+h] = b_v[h]

__global__ void prep_kernel(const float* __restrict__ P,
                            const float* __restrict__ b_v,
                            const float* __restrict__ K,
                            const float* __restrict__ C,
                            const float* __restrict__ P_z,
                            const float* __restrict__ b_z,
                            const float* __restrict__ e_e,
                            const float* __restrict__ e_i,
                            float* __restrict__ ws)
{
    const float ee = e_e[0];
    const float ei = e_i[0];
    for (int idx = threadIdx.x; idx < 2304; idx += blockDim.x) {
        const int h = idx / 48;
        const int k = idx % 48;
        const float ksp = log1pf(expf(K[idx]));
        const float csp = log1pf(expf(C[idx]));
        const float S   = ksp + csp;
        // cols < 24 excitatory: relu(ee*S) >= 0 ; cols >= 24 inhibitory: <= 0
        const float w = (k < 24) ? fmaxf(0.0f, ee * S) : fminf(0.0f, ei * S);
        ws[k * 96 + h]      = ksp;
        ws[k * 96 + 48 + h] = w;
    }
    for (int idx = threadIdx.x; idx < 384; idx += blockDim.x) {
        const int h = idx / 8;
        const int j = idx % 8;
        const float mask = ((h / 12) & 1) ? 0.0f : 1.0f;   // rows [12,24)+[36,48) off
        ws[4608 + j * 96 + h]      = P_z[idx];
        ws[4608 + j * 96 + 48 + h] = P[idx] * mask;
    }
    for (int idx = threadIdx.x; idx < 48; idx += blockDim.x) {
        ws[5376 + idx]      = b_z[idx];
        ws[5376 + 48 + idx] = b_v[idx];
    }
}

__device__ __forceinline__ float fast_sigmoid(float v) {
    const float e = __expf(-v);
    return __builtin_amdgcn_rcpf(1.0f + e);
}

__device__ __forceinline__ unsigned bf16_rn(float f) {
    unsigned u = __float_as_uint(f);
    u += 0x7FFFu + ((u >> 16) & 1u);
    return u >> 16;
}

__global__ void __launch_bounds__(256, 4)
dale_main(const float* __restrict__ hidden,
          const float* __restrict__ x,
          const float* __restrict__ ws,
          float* __restrict__ out,
          int B)
{
    __shared__ unsigned r_lds[24 * 256];   // [k-pair][tid], bank=tid%32, 2-way free
    const int tid = threadIdx.x;
    const long b = (long)blockIdx.x * 256 + tid;
    if (b >= B) return;                    // no barriers used -> early-out safe

    const float* __restrict__ WB = ws;
    const float* __restrict__ PB = ws + 4608;
    const float* __restrict__ bb = ws + 5376;

    // ---- load hidden row, compute r = sigmoid(v), pack bf16x2 -> LDS ----
    {
        const float4* hp = reinterpret_cast<const float4*>(hidden + b * 48);
        #pragma unroll
        for (int i = 0; i < 12; ++i) {
            const float4 t = hp[i];
            const unsigned p0 = bf16_rn(fast_sigmoid(t.x)) | (bf16_rn(fast_sigmoid(t.y)) << 16);
            const unsigned p1 = bf16_rn(fast_sigmoid(t.z)) | (bf16_rn(fast_sigmoid(t.w)) << 16);
            r_lds[(2 * i + 0) * 256 + tid] = p0;   // k = 4i, 4i+1
            r_lds[(2 * i + 1) * 256 + tid] = p1;   // k = 4i+2, 4i+3
        }
    }

    // ---- accumulators: acc1 = z-path, acc2 = v-path ----
    float acc1[48], acc2[48];
    #pragma unroll
    for (int h = 0; h < 48; ++h) { acc1[h] = bb[h]; acc2[h] = bb[48 + h]; }

    // input projections (8 x 96 FMAs)
    #pragma unroll
    for (int j = 0; j < 8; ++j) {
        const float xj = x[(long)j * B + b];
        const float* pb = PB + j * 96;
        #pragma unroll
        for (int h = 0; h < 48; ++h) {
            acc1[h] = fmaf(pb[h],      xj, acc1[h]);
            acc2[h] = fmaf(pb[48 + h], xj, acc2[h]);
        }
    }

    // ---- fused recurrent pass: 24 k-pairs, 192 FMAs each ----
    const unsigned* rc = &r_lds[tid];
    unsigned cur = rc[0];
    #pragma unroll 1
    for (int kp = 0; kp < 24; ++kp) {
        const unsigned nxt = (kp < 23) ? rc[(kp + 1) * 256] : cur;  // prefetch
        const float r0 = __uint_as_float(cur << 16);            // k = 2kp
        const float r1 = __uint_as_float(cur & 0xFFFF0000u);    // k = 2kp+1
        const float* w0 = WB + kp * 192;
        #pragma unroll
        for (int h = 0; h < 48; ++h) acc1[h] = fmaf(w0[h],       r0, acc1[h]);
        #pragma unroll
        for (int h = 0; h < 48; ++h) acc2[h] = fmaf(w0[48 + h],  r0, acc2[h]);
        #pragma unroll
        for (int h = 0; h < 48; ++h) acc1[h] = fmaf(w0[96 + h],  r1, acc1[h]);
        #pragma unroll
        for (int h = 0; h < 48; ++h) acc2[h] = fmaf(w0[144 + h], r1, acc2[h]);
        cur = nxt;
    }

    // ---- epilogue: re-read v (L3-resident), combine, store ----
    const float* hbase = hidden + b * 48;
    asm volatile("" : "+v"(hbase));        // force re-load, don't keep v live
    const float4* hp2 = reinterpret_cast<const float4*>(hbase);
    float4* op = reinterpret_cast<float4*>(out + b * 48);
    #pragma unroll
    for (int i = 0; i < 12; ++i) {
        const float4 v = hp2[i];
        float4 o;
        {
            const float z = DTC * fast_sigmoid(acc1[4 * i + 0]);
            o.x = fmaf(DTC, acc2[4 * i + 0], v.x * (1.0f - z));
        }
        {
            const float z = DTC * fast_sigmoid(acc1[4 * i + 1]);
            o.y = fmaf(DTC, acc2[4 * i + 1], v.y * (1.0f - z));
        }
        {
            const float z = DTC * fast_sigmoid(acc1[4 * i + 2]);
            o.z = fmaf(DTC, acc2[4 * i + 2], v.z * (1.0f - z));
        }
        {
            const float z = DTC * fast_sigmoid(acc1[4 * i + 3]);
            o.w = fmaf(DTC, acc2[4 * i + 3], v.w * (1.0f - z));
        }
        op[i] = o;
    }
}

extern "C" void kernel_launch(void* const* d_in, const int* in_sizes, int n_in,
                              void* d_out, int out_size, void* d_ws, size_t ws_size,
                              hipStream_t stream) {
    const float* hidden = (const float*)d_in[0];
    const float* x      = (const float*)d_in[1];
    const float* P      = (const float*)d_in[2];
    const float* b_v    = (const float*)d_in[3];
    const float* K      = (const float*)d_in[4];
    const float* C      = (const float*)d_in[5];
    const float* P_z    = (const float*)d_in[6];
    const float* b_z    = (const float*)d_in[7];
    const float* e_e    = (const float*)d_in[8];
    const float* e_i    = (const float*)d_in[9];
    float* out = (float*)d_out;
    float* ws  = (float*)d_ws;
    const int B = in_sizes[0] / 48;

    prep_kernel<<<dim3(1), dim3(256), 0, stream>>>(P, b_v, K, C, P_z, b_z, e_e, e_i, ws);
    dale_main<<<dim3((B + 255) / 256), dim3(256), 0, stream>>>(hidden, x, ws, out, B);
}

// Round 4
// 418.334 us; speedup vs baseline: 1.5634x; 1.5634x over previous
//
#include <hip/hip_runtime.h>
#include <math.h>

// Dale CB-cell recurrent update. H=48, IN=8, B=1048576, DT=0.1, fp32 in/out.
//
// R3 (resubmit; R3 bench never acquired a GPU): MFMA formulation.
// Augmented GEMM: C(96 x B) = A_aug(96 x 64) @ B_aug(64 x B)
//   A_aug rows 0..47  = [softplus(K) | P_z      | b_z | 0...]   (z-path)
//   A_aug rows 48..95 = [Dale W      | P*mask   | b_v | 0...]   (v-path)
//   B_aug cols        = [sigmoid(v) ; x ; 1 ; 0...]  per batch element, bf16.
// Per 256-thread block: stage 256 elements into LDS [elem][k] bf16 rows
// (128B/row, XOR-16B swizzled), then 4 waves x 4 subtiles x 12 mfma 16x16x32.
// Epilogue re-reads hidden (block-hot in L1/L2) and applies sigmoid/combine.
// prep_kernel pre-bakes A-fragments in exact lane order into d_ws.

#define DTC 0.1f

typedef __attribute__((ext_vector_type(8))) short bf16x8;
typedef __attribute__((ext_vector_type(4))) float f32x4;

__device__ __forceinline__ unsigned bf16_rn(float f) {
    unsigned u = __float_as_uint(f);
    u += 0x7FFFu + ((u >> 16) & 1u);
    return u >> 16;
}

__device__ __forceinline__ float fast_sigmoid(float v) {
    const float e = __expf(-v);
    return __builtin_amdgcn_rcpf(1.0f + e);
}

// ws: 12 fragments x 64 lanes x 8 bf16 (12288 bytes).
// frag fi = mt*2+ks holds A_aug[m = mt*16 + (l&15)][k = ks*32 + (l>>4)*8 + j].
__global__ void prep_kernel(const float* __restrict__ P,
                            const float* __restrict__ b_v,
                            const float* __restrict__ K,
                            const float* __restrict__ C,
                            const float* __restrict__ P_z,
                            const float* __restrict__ b_z,
                            const float* __restrict__ e_e,
                            const float* __restrict__ e_i,
                            unsigned short* __restrict__ ws16)
{
    const float ee = e_e[0];
    const float ei = e_i[0];
    for (int idx = threadIdx.x; idx < 6144; idx += blockDim.x) {
        const int fi  = idx >> 9;          // 0..11
        const int rem = idx & 511;
        const int l   = rem >> 3;          // lane 0..63
        const int j   = rem & 7;
        const int mt  = fi >> 1;
        const int ks  = fi & 1;
        const int m   = mt * 16 + (l & 15);      // 0..95
        const int k   = ks * 32 + ((l >> 4) << 3) + j;  // 0..63
        const bool zp = (m < 48);
        const int h   = zp ? m : m - 48;
        float val;
        if (k < 48) {
            const float ksp = log1pf(expf(K[h * 48 + k]));
            if (zp) {
                val = ksp;
            } else {
                const float S = ksp + log1pf(expf(C[h * 48 + k]));
                // cols <24 excitatory: relu(ee*S)>=0 ; cols >=24 inhibitory: <=0
                val = (k < 24) ? fmaxf(0.0f, ee * S) : fminf(0.0f, ei * S);
            }
        } else if (k < 56) {
            const int jj = k - 48;
            if (zp) {
                val = P_z[h * 8 + jj];
            } else {
                const float mask = ((h / 12) & 1) ? 0.0f : 1.0f;  // rows [12,24)+[36,48) off
                val = P[h * 8 + jj] * mask;
            }
        } else if (k == 56) {
            val = zp ? b_z[h] : b_v[h];
        } else {
            val = 0.0f;
        }
        ws16[idx] = (unsigned short)bf16_rn(val);
    }
}

__global__ void __launch_bounds__(256)
dale_main(const float* __restrict__ hidden,
          const float* __restrict__ x,
          const unsigned short* __restrict__ ws16,
          float* __restrict__ out,
          int B)
{
    __shared__ unsigned lds[256 * 32];     // [elem row: 32 uints = 64 bf16 (k)]
    const int tid  = threadIdx.x;
    const int wave = tid >> 6;
    const int lane = tid & 63;
    const long bb  = (long)blockIdx.x * 256;

    // ---- stage: build this element's augmented bf16 column into LDS row ----
    {
        const long gb = (bb + tid < (long)B) ? (bb + tid) : (long)B - 1;
        const float4* hp = reinterpret_cast<const float4*>(hidden + gb * 48);
        const unsigned rowbase = tid * 32;
        const unsigned sw = (tid & 7);
        #pragma unroll
        for (int c = 0; c < 6; ++c) {       // k = 8c .. 8c+8 : sigmoid(v)
            const float4 a = hp[2 * c];
            const float4 b = hp[2 * c + 1];
            uint4 w;
            w.x = bf16_rn(fast_sigmoid(a.x)) | (bf16_rn(fast_sigmoid(a.y)) << 16);
            w.y = bf16_rn(fast_sigmoid(a.z)) | (bf16_rn(fast_sigmoid(a.w)) << 16);
            w.z = bf16_rn(fast_sigmoid(b.x)) | (bf16_rn(fast_sigmoid(b.y)) << 16);
            w.w = bf16_rn(fast_sigmoid(b.z)) | (bf16_rn(fast_sigmoid(b.w)) << 16);
            *reinterpret_cast<uint4*>(&lds[rowbase + 4 * (c ^ sw)]) = w;
        }
        {                                   // k = 48..56 : x, then 1.0, zeros
            float xv[8];
            #pragma unroll
            for (int j = 0; j < 8; ++j) xv[j] = x[(long)j * B + gb];
            uint4 w6;
            w6.x = bf16_rn(xv[0]) | (bf16_rn(xv[1]) << 16);
            w6.y = bf16_rn(xv[2]) | (bf16_rn(xv[3]) << 16);
            w6.z = bf16_rn(xv[4]) | (bf16_rn(xv[5]) << 16);
            w6.w = bf16_rn(xv[6]) | (bf16_rn(xv[7]) << 16);
            *reinterpret_cast<uint4*>(&lds[rowbase + 4 * (6 ^ sw)]) = w6;
            uint4 w7;
            w7.x = 0x00003F80u;             // bf16(1.0) at k=56, rest zero
            w7.y = 0u; w7.z = 0u; w7.w = 0u;
            *reinterpret_cast<uint4*>(&lds[rowbase + 4 * (7 ^ sw)]) = w7;
        }
    }
    __syncthreads();

    // ---- A fragments (wave-identical, from prep-baked ws) ----
    bf16x8 A[12];
    {
        const bf16x8* ap = reinterpret_cast<const bf16x8*>(ws16);
        #pragma unroll
        for (int i = 0; i < 12; ++i) A[i] = ap[i * 64 + lane];
    }

    // ---- 4 subtiles of 16 elements per wave ----
    #pragma unroll 1
    for (int s = 0; s < 4; ++s) {
        const int row = wave * 64 + s * 16 + (lane & 15);   // LDS elem row
        const unsigned rsw = (row & 7);
        const unsigned c0 = (unsigned)(lane >> 4);          // kstep0 chunk
        const bf16x8 B0 = *reinterpret_cast<const bf16x8*>(&lds[row * 32 + 4 * (c0 ^ rsw)]);
        const bf16x8 B1 = *reinterpret_cast<const bf16x8*>(&lds[row * 32 + 4 * ((c0 + 4) ^ rsw)]);

        f32x4 acc[6];
        #pragma unroll
        for (int t = 0; t < 6; ++t) acc[t] = (f32x4){0.f, 0.f, 0.f, 0.f};
        #pragma unroll
        for (int t = 0; t < 6; ++t) {
            acc[t] = __builtin_amdgcn_mfma_f32_16x16x32_bf16(A[t * 2 + 0], B0, acc[t], 0, 0, 0);
            acc[t] = __builtin_amdgcn_mfma_f32_16x16x32_bf16(A[t * 2 + 1], B1, acc[t], 0, 0, 0);
        }

        // ---- epilogue: lane holds elem col = row, h = t*16 + (lane>>4)*4 + r ----
        const long ge = bb + row;
        const bool ok = (ge < (long)B);
        const long gc = ok ? ge : (long)B - 1;
        const float4* vp = reinterpret_cast<const float4*>(hidden + gc * 48) + (lane >> 4);
        float4*       op = reinterpret_cast<float4*>(out + gc * 48) + (lane >> 4);
        #pragma unroll
        for (int t = 0; t < 3; ++t) {
            const float4 v = vp[t * 4];
            const f32x4 az = acc[t];
            const f32x4 av = acc[t + 3];
            float4 o;
            o.x = fmaf(DTC, av[0], v.x * (1.0f - DTC * fast_sigmoid(az[0])));
            o.y = fmaf(DTC, av[1], v.y * (1.0f - DTC * fast_sigmoid(az[1])));
            o.z = fmaf(DTC, av[2], v.z * (1.0f - DTC * fast_sigmoid(az[2])));
            o.w = fmaf(DTC, av[3], v.w * (1.0f - DTC * fast_sigmoid(az[3])));
            if (ok) op[t * 4] = o;
        }
    }
}

extern "C" void kernel_launch(void* const* d_in, const int* in_sizes, int n_in,
                              void* d_out, int out_size, void* d_ws, size_t ws_size,
                              hipStream_t stream) {
    const float* hidden = (const float*)d_in[0];
    const float* x      = (const float*)d_in[1];
    const float* P      = (const float*)d_in[2];
    const float* b_v    = (const float*)d_in[3];
    const float* K      = (const float*)d_in[4];
    const float* C      = (const float*)d_in[5];
    const float* P_z    = (const float*)d_in[6];
    const float* b_z    = (const float*)d_in[7];
    const float* e_e    = (const float*)d_in[8];
    const float* e_i    = (const float*)d_in[9];
    float* out = (float*)d_out;
    unsigned short* ws16 = (unsigned short*)d_ws;
    const int B = in_sizes[0] / 48;

    prep_kernel<<<dim3(1), dim3(256), 0, stream>>>(P, b_v, K, C, P_z, b_z, e_e, e_i, ws16);
    dale_main<<<dim3((B + 255) / 256), dim3(256), 0, stream>>>(hidden, x, ws16, out, B);
}

// Round 10
// 396.394 us; speedup vs baseline: 1.6499x; 1.0553x over previous
//
#include <hip/hip_runtime.h>
#include <math.h>

// Dale CB-cell recurrent update. H=48, IN=8, B=1048576, DT=0.1, fp32 in/out.
//
// R5 (6th submit; prior five benches died on infra, kernel never ran):
// wave-private barrier-free pipeline. Augmented GEMM
// C(96 x B) = A_aug(96 x 64) @ B_aug(64 x B), bf16 MFMA 16x16x32:
//   A rows 0..47  = [softplus(K) | P_z    | b_z | 0]   (z-path)
//   A rows 48..95 = [Dale W      | P*mask | b_v | 0]   (v-path)
//   B cols        = [sigmoid(v) ; x ; 1 ; 0] per batch element.
// Each WAVE owns a 32-element micro-tile and a private LDS slice:
//   r: [32][8 chunks of 16B] bf16, XOR-swizzled   (4 KB)
//   v: [32][52] fp32 (pad 48->52: conflict-free + 16B-aligned)  (6.5 KB)
// No __syncthreads anywhere -> register prefetch of tile t+1 stays in flight
// across tile t's MFMA+epilogue. 8 tiles per wave; grid 1024 x 256.

#define DTC 0.1f
#define TPW 8   // tiles of 32 elements per wave

typedef __attribute__((ext_vector_type(8))) short bf16x8;
typedef __attribute__((ext_vector_type(4))) float f32x4;

__device__ __forceinline__ unsigned bf16_rn(float f) {
    unsigned u = __float_as_uint(f);
    u += 0x7FFFu + ((u >> 16) & 1u);
    return u >> 16;
}

__device__ __forceinline__ float fast_sigmoid(float v) {
    const float e = __expf(-v);
    return __builtin_amdgcn_rcpf(1.0f + e);
}

__device__ __forceinline__ uint4 pack_sig(const float4 a, const float4 b) {
    uint4 w;
    w.x = bf16_rn(fast_sigmoid(a.x)) | (bf16_rn(fast_sigmoid(a.y)) << 16);
    w.y = bf16_rn(fast_sigmoid(a.z)) | (bf16_rn(fast_sigmoid(a.w)) << 16);
    w.z = bf16_rn(fast_sigmoid(b.x)) | (bf16_rn(fast_sigmoid(b.y)) << 16);
    w.w = bf16_rn(fast_sigmoid(b.z)) | (bf16_rn(fast_sigmoid(b.w)) << 16);
    return w;
}

// ws: 12 fragments x 64 lanes x 8 bf16 (12288 B).
// frag fi = mt*2+ks holds A_aug[m = mt*16 + (l&15)][k = ks*32 + (l>>4)*8 + j].
__global__ void prep_kernel(const float* __restrict__ P,
                            const float* __restrict__ b_v,
                            const float* __restrict__ K,
                            const float* __restrict__ C,
                            const float* __restrict__ P_z,
                            const float* __restrict__ b_z,
                            const float* __restrict__ e_e,
                            const float* __restrict__ e_i,
                            unsigned short* __restrict__ ws16)
{
    const float ee = e_e[0];
    const float ei = e_i[0];
    for (int idx = threadIdx.x; idx < 6144; idx += blockDim.x) {
        const int fi  = idx >> 9;
        const int rem = idx & 511;
        const int l   = rem >> 3;
        const int j   = rem & 7;
        const int mt  = fi >> 1;
        const int ks  = fi & 1;
        const int m   = mt * 16 + (l & 15);
        const int k   = ks * 32 + ((l >> 4) << 3) + j;
        const bool zp = (m < 48);
        const int h   = zp ? m : m - 48;
        float val;
        if (k < 48) {
            const float ksp = log1pf(expf(K[h * 48 + k]));
            if (zp) {
                val = ksp;
            } else {
                const float S = ksp + log1pf(expf(C[h * 48 + k]));
                val = (k < 24) ? fmaxf(0.0f, ee * S) : fminf(0.0f, ei * S);
            }
        } else if (k < 56) {
            const int jj = k - 48;
            if (zp) {
                val = P_z[h * 8 + jj];
            } else {
                const float mask = ((h / 12) & 1) ? 0.0f : 1.0f;
                val = P[h * 8 + jj] * mask;
            }
        } else if (k == 56) {
            val = zp ? b_z[h] : b_v[h];
        } else {
            val = 0.0f;
        }
        ws16[idx] = (unsigned short)bf16_rn(val);
    }
}

__global__ void __launch_bounds__(256, 3)
dale_main(const float* __restrict__ hidden,
          const float* __restrict__ x,
          const unsigned short* __restrict__ ws16,
          float* __restrict__ out,
          int B)
{
    __shared__ unsigned r_lds[4][32 * 32];   // [wave][row*32w]: 8x16B swz chunks
    __shared__ float    v_lds[4][32 * 52];   // [wave][row*52]: fp32 v, padded
    const int tid  = threadIdx.x;
    const int wave = tid >> 6;
    const int lane = tid & 63;
    const int el   = lane >> 1;              // staging: element-local 0..31
    const int p    = lane & 1;               // staging: which 24-value half
    unsigned* rl = r_lds[wave];
    float*    vl = v_lds[wave];

    // A fragments, loop-invariant
    bf16x8 A[12];
    {
        const bf16x8* ap = reinterpret_cast<const bf16x8*>(ws16);
        #pragma unroll
        for (int i = 0; i < 12; ++i) A[i] = ap[i * 64 + lane];
    }

    const long wt0 = ((long)blockIdx.x * 4 + wave) * TPW;

    // prefetch registers
    float4 H[6]; float X[8];
    {
        const long eb = wt0 * 32;
        const float4* hp = reinterpret_cast<const float4*>(hidden + (eb + el) * 48) + p * 6;
        #pragma unroll
        for (int i = 0; i < 6; ++i) H[i] = hp[i];
        if (p) {
            #pragma unroll
            for (int j = 0; j < 8; ++j) X[j] = x[(long)j * B + eb + el];
        }
    }

    #pragma unroll 1
    for (int it = 0; it < TPW; ++it) {
        const long eb = (wt0 + it) * 32;

        // ---- stage tile it from regs (auto vmcnt wait on H/X first use) ----
        const unsigned rowbase = el * 32;
        const unsigned sw = el & 7;
        #pragma unroll
        for (int c = 0; c < 3; ++c) {
            const uint4 w = pack_sig(H[2 * c], H[2 * c + 1]);
            *reinterpret_cast<uint4*>(&rl[rowbase + 4 * (((p * 3 + c)) ^ sw)]) = w;
        }
        if (p) {                              // chunk 6: x (k=48..55)
            uint4 w6;
            w6.x = bf16_rn(X[0]) | (bf16_rn(X[1]) << 16);
            w6.y = bf16_rn(X[2]) | (bf16_rn(X[3]) << 16);
            w6.z = bf16_rn(X[4]) | (bf16_rn(X[5]) << 16);
            w6.w = bf16_rn(X[6]) | (bf16_rn(X[7]) << 16);
            *reinterpret_cast<uint4*>(&rl[rowbase + 4 * (6 ^ sw)]) = w6;
        } else {                              // chunk 7: bias 1.0 + zeros
            uint4 w7;
            w7.x = 0x00003F80u; w7.y = 0u; w7.z = 0u; w7.w = 0u;
            *reinterpret_cast<uint4*>(&rl[rowbase + 4 * (7 ^ sw)]) = w7;
        }
        {                                     // fp32 v -> LDS (epilogue source)
            float* vrow = vl + el * 52 + p * 24;
            #pragma unroll
            for (int i = 0; i < 6; ++i)
                *reinterpret_cast<float4*>(vrow + 4 * i) = H[i];
        }

        // ---- issue prefetch for tile it+1 (stays in flight over compute) ----
        if (it + 1 < TPW) {
            const long nb = (wt0 + it + 1) * 32;
            const float4* hp = reinterpret_cast<const float4*>(hidden + (nb + el) * 48) + p * 6;
            #pragma unroll
            for (int i = 0; i < 6; ++i) H[i] = hp[i];
            if (p) {
                #pragma unroll
                for (int j = 0; j < 8; ++j) X[j] = x[(long)j * B + nb + el];
            }
        }
        __builtin_amdgcn_sched_barrier(0);    // don't sink the prefetch

        // ---- compute: 2 subtiles of 16 elements ----
        #pragma unroll 1
        for (int s = 0; s < 2; ++s) {
            const int row = s * 16 + (lane & 15);
            const unsigned rsw = row & 7;
            const unsigned c0 = (unsigned)(lane >> 4);
            const bf16x8 B0 = *reinterpret_cast<const bf16x8*>(&rl[row * 32 + 4 * (c0 ^ rsw)]);
            const bf16x8 B1 = *reinterpret_cast<const bf16x8*>(&rl[row * 32 + 4 * ((c0 + 4) ^ rsw)]);

            f32x4 acc[6];
            #pragma unroll
            for (int t = 0; t < 6; ++t) acc[t] = (f32x4){0.f, 0.f, 0.f, 0.f};
            #pragma unroll
            for (int t = 0; t < 6; ++t) {
                acc[t] = __builtin_amdgcn_mfma_f32_16x16x32_bf16(A[t * 2 + 0], B0, acc[t], 0, 0, 0);
                acc[t] = __builtin_amdgcn_mfma_f32_16x16x32_bf16(A[t * 2 + 1], B1, acc[t], 0, 0, 0);
            }

            // epilogue: lane's element = eb+row; h = 16t + (lane>>4)*4 + r
            const long ge = eb + row;
            const float* vp = vl + row * 52 + (lane >> 4) * 4;
            float4* op = reinterpret_cast<float4*>(out + ge * 48) + (lane >> 4);
            #pragma unroll
            for (int t = 0; t < 3; ++t) {
                const float4 v = *reinterpret_cast<const float4*>(vp + 16 * t);
                const f32x4 az = acc[t];
                const f32x4 av = acc[t + 3];
                float4 o;
                o.x = fmaf(DTC, av[0], v.x * (1.0f - DTC * fast_sigmoid(az[0])));
                o.y = fmaf(DTC, av[1], v.y * (1.0f - DTC * fast_sigmoid(az[1])));
                o.z = fmaf(DTC, av[2], v.z * (1.0f - DTC * fast_sigmoid(az[2])));
                o.w = fmaf(DTC, av[3], v.w * (1.0f - DTC * fast_sigmoid(az[3])));
                op[t * 4] = o;
            }
        }
    }
}

extern "C" void kernel_launch(void* const* d_in, const int* in_sizes, int n_in,
                              void* d_out, int out_size, void* d_ws, size_t ws_size,
                              hipStream_t stream) {
    const float* hidden = (const float*)d_in[0];
    const float* x      = (const float*)d_in[1];
    const float* P      = (const float*)d_in[2];
    const float* b_v    = (const float*)d_in[3];
    const float* K      = (const float*)d_in[4];
    const float* C      = (const float*)d_in[5];
    const float* P_z    = (const float*)d_in[6];
    const float* b_z    = (const float*)d_in[7];
    const float* e_e    = (const float*)d_in[8];
    const float* e_i    = (const float*)d_in[9];
    float* out = (float*)d_out;
    unsigned short* ws16 = (unsigned short*)d_ws;
    const int B = in_sizes[0] / 48;

    prep_kernel<<<dim3(1), dim3(256), 0, stream>>>(P, b_v, K, C, P_z, b_z, e_e, e_i, ws16);
    // B = 1048576 = 1024 blocks * 4 waves * TPW(8) * 32 elements
    const int nblocks = B / (4 * TPW * 32);
    dale_main<<<dim3(nblocks), dim3(256), 0, stream>>>(hidden, x, ws16, out, B);
}